// Round 5
// baseline (1593.106 us; speedup 1.0000x reference)
//
#include <hip/hip_runtime.h>
#include <math.h>

#define NN 100000
#define NE 1000000
#define D 64
#define L 3
#define RVQ 3
#define CODES 16
#define BN_EPS 1e-5f
#define COMMIT_W 0.25f

#define GRID_A 2048   // blocks for matvec/layer_b kernels (fixed: partials + node mapping)

// ---------------- ws layout (in 4-byte units) ----------------
#define OFS_ROWPTR 0           // 100001 ints
#define OFS_CNT    100016      // 100000 ints
#define OFS_CURSOR 200032      // 100000 ints
#define OFS_BSUMS  300048      // 128 ints
#define OFS_BOFFS  300176      // 128 ints
#define OFS_STATS  300304      // 3*128 floats (sum[64],sumsq[64] per layer)
#define OFS_CSR    300800      // 1000000 ints
#define OFS_HA     1300800     // 6400000 floats
#define OFS_HB     7700800     // 6400000 floats
#define OFS_XLOC   14100800    // 6400000 floats
#define OFS_PART   20500800    // 2048*128 floats = 262144
// total = 20,762,944 * 4 B ~= 83 MB

// ---------------- d_out layout (floats) ----------------
#define OUT_PRED   0
#define OUT_COMMIT (NN * D)                       // 6,400,000
#define OUT_IDS    (NN * D + 1)                   // 6,400,001
#define OUT_GNN    (NN * D + 1 + NN * (L * RVQ))  // 7,300,001

static __device__ __forceinline__ float waveSum(float v) {
    #pragma unroll
    for (int off = 32; off; off >>= 1) v += __shfl_xor(v, off, 64);
    return v;
}

// ---------------- CSR build ----------------
__global__ void k_count(const int* __restrict__ dst, int* __restrict__ cnt) {
    int e = blockIdx.x * blockDim.x + threadIdx.x;
    if (e < NE) atomicAdd(&cnt[dst[e]], 1);
}

#define SCAN_B 1024
__global__ void k_scan1(const int* __restrict__ cnt, int* __restrict__ rowptr,
                        int* __restrict__ bsums) {
    __shared__ int sm[SCAN_B];
    int t = threadIdx.x;
    int i = blockIdx.x * SCAN_B + t;
    int v = (i < NN) ? cnt[i] : 0;
    sm[t] = v;
    __syncthreads();
    for (int off = 1; off < SCAN_B; off <<= 1) {
        int add = (t >= off) ? sm[t - off] : 0;
        __syncthreads();
        sm[t] += add;
        __syncthreads();
    }
    if (i < NN) rowptr[i + 1] = sm[t];
    if (t == SCAN_B - 1) bsums[blockIdx.x] = sm[t];
}

__global__ void k_scan2(const int* __restrict__ bsums, int* __restrict__ boffs, int nb) {
    __shared__ int sm[SCAN_B];
    int t = threadIdx.x;
    int orig = (t < nb) ? bsums[t] : 0;
    sm[t] = orig;
    __syncthreads();
    for (int off = 1; off < SCAN_B; off <<= 1) {
        int add = (t >= off) ? sm[t - off] : 0;
        __syncthreads();
        sm[t] += add;
        __syncthreads();
    }
    if (t < nb) boffs[t] = sm[t] - orig;  // exclusive
}

__global__ void k_scan3(int* __restrict__ rowptr, const int* __restrict__ boffs) {
    int i = blockIdx.x * SCAN_B + threadIdx.x;
    if (i < NN) rowptr[i + 1] += boffs[blockIdx.x];
    if (i == 0) rowptr[0] = 0;
}

__global__ void k_cursor(const int* __restrict__ rowptr, int* __restrict__ cursor) {
    int i = blockIdx.x * blockDim.x + threadIdx.x;
    if (i < NN) cursor[i] = rowptr[i];
}

__global__ void k_fill(const int* __restrict__ src, const int* __restrict__ dst,
                       int* __restrict__ cursor, int* __restrict__ csr_src) {
    int e = blockIdx.x * blockDim.x + threadIdx.x;
    if (e < NE) {
        int p = atomicAdd(&cursor[dst[e]], 1);
        csr_src[p] = src[e];
    }
}

// Canonicalize row order so the neighbor-sum order is deterministic.
__global__ void k_sortrows(const int* __restrict__ rowptr, int* __restrict__ csr) {
    int n = blockIdx.x * blockDim.x + threadIdx.x;
    if (n >= NN) return;
    int r0 = rowptr[n], r1 = rowptr[n + 1];
    for (int i = r0 + 1; i < r1; ++i) {
        int v = csr[i];
        int j = i - 1;
        while (j >= r0 && csr[j] > v) { csr[j + 1] = csr[j]; --j; }
        csr[j + 1] = v;
    }
}

// ---------------- Gather: mean of neighbor rows -> mean_out ----------------
// 4 nodes per wave: quarter q (16 lanes) handles node wave*4+q; lane covers 4
// channels via float4. 4-deep unroll -> 16 rows in flight per wave (4x the old
// MLP). Per-channel accumulation remains strictly ascending over the sorted
// CSR row -> bit-identical to previous rounds.
__global__ __launch_bounds__(256) void k_gather(
    const float* __restrict__ h, const int* __restrict__ rowptr,
    const int* __restrict__ csr_src, float* __restrict__ mean_out) {
    int t = threadIdx.x;
    int lane = t & 63, wid = t >> 6;
    int q = lane >> 4;          // quarter 0..3
    int p = lane & 15;          // lane within quarter
    int qbase = q << 4;
    int wavei = blockIdx.x * 4 + wid;
    int n = wavei * 4 + q;
    if (n >= NN) return;

    int r0 = rowptr[n], r1 = rowptr[n + 1];
    float4 s = {0.f, 0.f, 0.f, 0.f};
    for (int base = r0; base < r1; base += 16) {
        int last = r1 - 1;
        int ii = base + p;
        int idx = csr_src[(ii <= last) ? ii : last];  // coalesced (16 lanes), clamped
        int m = r1 - base;
        if (m > 16) m = 16;
        int j = 0;
        for (; j + 4 <= m; j += 4) {
            int i0 = __shfl(idx, qbase + j + 0, 64);
            int i1 = __shfl(idx, qbase + j + 1, 64);
            int i2 = __shfl(idx, qbase + j + 2, 64);
            int i3 = __shfl(idx, qbase + j + 3, 64);
            float4 v0 = *(const float4*)(h + (size_t)i0 * D + 4 * p);
            float4 v1 = *(const float4*)(h + (size_t)i1 * D + 4 * p);
            float4 v2 = *(const float4*)(h + (size_t)i2 * D + 4 * p);
            float4 v3 = *(const float4*)(h + (size_t)i3 * D + 4 * p);
            s.x += v0.x; s.y += v0.y; s.z += v0.z; s.w += v0.w;
            s.x += v1.x; s.y += v1.y; s.z += v1.z; s.w += v1.w;
            s.x += v2.x; s.y += v2.y; s.z += v2.z; s.w += v2.w;
            s.x += v3.x; s.y += v3.y; s.z += v3.z; s.w += v3.w;
        }
        for (; j < m; ++j) {
            int i0 = __shfl(idx, qbase + j, 64);
            float4 v0 = *(const float4*)(h + (size_t)i0 * D + 4 * p);
            s.x += v0.x; s.y += v0.y; s.z += v0.z; s.w += v0.w;
        }
    }
    float deg = fmaxf((float)(r1 - r0), 1.0f);
    float4 mean4;
    mean4.x = s.x / deg;
    mean4.y = s.y / deg;
    mean4.z = s.z / deg;
    mean4.w = s.w / deg;
    *(float4*)(mean_out + (size_t)n * D + 4 * p) = mean4;
}

// ---------------- Matvec: SAGE transform + skip linear + BN stat partials --
// lane = output channel; weights per-lane (ideally register-resident).
// Activation rows loaded as uniform-address VECTOR loads (vmcnt, in-order ->
// pipelines under FMAs, unlike SMEM's lgkmcnt(0) drain). Two nodes per
// iteration amortize the weight access 2x and double independent FMA chains.
// Accumulation order per output is k-ascending and accS/accQ stay
// node-ascending -> bit-identical to previous rounds.
__global__ __launch_bounds__(256) void k_matvec(
    const float* __restrict__ h, float* __restrict__ hp,
    const float* __restrict__ Wa, const float* __restrict__ ba,
    const float* __restrict__ Wr, const float* __restrict__ Wl,
    const float* __restrict__ bl, float* __restrict__ partials) {
    __shared__ float red[2][4][D];
    int t = threadIdx.x, lane = t & 63, wid = t >> 6;

    float wa[D], wr[D], wl[D];
    #pragma unroll
    for (int k = 0; k < D; ++k) {
        wa[k] = Wa[k * D + lane];
        wr[k] = Wr[k * D + lane];
        wl[k] = Wl[k * D + lane];
    }
    float bav = ba[lane], blv = bl[lane];

    int wg = blockIdx.x * 4 + wid;
    const int wstep = GRID_A * 4;
    float accS = 0.f, accQ = 0.f;

    int n = wg;
    for (; n + wstep < NN; n += 2 * wstep) {
        int nA = n, nB = n + wstep;
        const float4* mrA = (const float4*)(hp + (size_t)nA * D);
        const float4* hrA = (const float4*)(h + (size_t)nA * D);
        const float4* mrB = (const float4*)(hp + (size_t)nB * D);
        const float4* hrB = (const float4*)(h + (size_t)nB * D);
        float aA = 0.f, rA = 0.f, lA = 0.f;
        float aB = 0.f, rB = 0.f, lB = 0.f;
        #pragma unroll
        for (int j = 0; j < 16; ++j) {
            float4 ma = mrA[j], ha = hrA[j];
            float4 mb = mrB[j], hb = hrB[j];
            aA += ma.x * wa[4 * j + 0]; rA += ha.x * wr[4 * j + 0]; lA += ha.x * wl[4 * j + 0];
            aA += ma.y * wa[4 * j + 1]; rA += ha.y * wr[4 * j + 1]; lA += ha.y * wl[4 * j + 1];
            aA += ma.z * wa[4 * j + 2]; rA += ha.z * wr[4 * j + 2]; lA += ha.z * wl[4 * j + 2];
            aA += ma.w * wa[4 * j + 3]; rA += ha.w * wr[4 * j + 3]; lA += ha.w * wl[4 * j + 3];
            aB += mb.x * wa[4 * j + 0]; rB += hb.x * wr[4 * j + 0]; lB += hb.x * wl[4 * j + 0];
            aB += mb.y * wa[4 * j + 1]; rB += hb.y * wr[4 * j + 1]; lB += hb.y * wl[4 * j + 1];
            aB += mb.z * wa[4 * j + 2]; rB += hb.z * wr[4 * j + 2]; lB += hb.z * wl[4 * j + 2];
            aB += mb.w * wa[4 * j + 3]; rB += hb.w * wr[4 * j + 3]; lB += hb.w * wl[4 * j + 3];
        }
        float sageA = aA + bav + rA;
        float ssA = waveSum(sageA * sageA);
        float invA = 1.0f / (sqrtf(ssA) + 1e-12f);
        float hpA = sageA * invA + lA + blv;
        hp[(size_t)nA * D + lane] = hpA;
        accS += hpA;
        accQ += hpA * hpA;
        float sageB = aB + bav + rB;
        float ssB = waveSum(sageB * sageB);
        float invB = 1.0f / (sqrtf(ssB) + 1e-12f);
        float hpB = sageB * invB + lB + blv;
        hp[(size_t)nB * D + lane] = hpB;
        accS += hpB;
        accQ += hpB * hpB;
    }
    for (; n < NN; n += wstep) {
        const float4* mrow = (const float4*)(hp + (size_t)n * D);
        const float4* hrow = (const float4*)(h + (size_t)n * D);
        float a = 0.f, r = 0.f, lv = 0.f;
        #pragma unroll
        for (int j = 0; j < 16; ++j) {
            float4 m4 = mrow[j];
            float4 h4 = hrow[j];
            a += m4.x * wa[4 * j + 0]; r += h4.x * wr[4 * j + 0]; lv += h4.x * wl[4 * j + 0];
            a += m4.y * wa[4 * j + 1]; r += h4.y * wr[4 * j + 1]; lv += h4.y * wl[4 * j + 1];
            a += m4.z * wa[4 * j + 2]; r += h4.z * wr[4 * j + 2]; lv += h4.z * wl[4 * j + 2];
            a += m4.w * wa[4 * j + 3]; r += h4.w * wr[4 * j + 3]; lv += h4.w * wl[4 * j + 3];
        }
        float sage = a + bav + r;
        float ss = waveSum(sage * sage);
        float inv = 1.0f / (sqrtf(ss) + 1e-12f);
        float hpv = sage * inv + lv + blv;
        hp[(size_t)n * D + lane] = hpv;
        accS += hpv;
        accQ += hpv * hpv;
    }

    red[0][wid][lane] = accS;
    red[1][wid][lane] = accQ;
    __syncthreads();
    if (wid == 0) {
        float s0 = (red[0][0][lane] + red[0][1][lane]) + (red[0][2][lane] + red[0][3][lane]);
        float q0 = (red[1][0][lane] + red[1][1][lane]) + (red[1][2][lane] + red[1][3][lane]);
        partials[blockIdx.x * 128 + lane]      = s0;
        partials[blockIdx.x * 128 + 64 + lane] = q0;
    }
}

// Deterministic fixed-order reduction of BN stat partials (no atomics).
__global__ void k_red_stats(const float* __restrict__ part, float* __restrict__ stats) {
    int t = threadIdx.x;  // 0..127
    float s0 = 0.f, s1 = 0.f, s2 = 0.f, s3 = 0.f;
    for (int b = 0; b < GRID_A; b += 4) {
        s0 += part[(b + 0) * 128 + t];
        s1 += part[(b + 1) * 128 + t];
        s2 += part[(b + 2) * 128 + t];
        s3 += part[(b + 3) * 128 + t];
    }
    stats[t] = (s0 + s1) + (s2 + s3);
}

// ---------------- Layer part B: BN + ReLU + x_local accumulate + residual VQ
#define CBSTRIDE 65
__global__ __launch_bounds__(256) void k_layer_b(
    float* __restrict__ hp,              // in: pre-BN h'; out: post-ReLU h
    const float* __restrict__ stats,
    const float* __restrict__ gamma, const float* __restrict__ beta,
    const float* __restrict__ cbs,       // [RVQ][CODES][D] for this layer
    float* __restrict__ x_local,
    float* __restrict__ ids_out,         // [NN][L*RVQ] region base
    int layer, float* __restrict__ commit, int first_layer) {
    __shared__ float scb[RVQ * CODES * CBSTRIDE];
    __shared__ float sres[256];
    __shared__ float sred[4];
    int t = threadIdx.x, lane = t & 63, wid = t >> 6;

    // normalize codebook rows into LDS (identical math to before)
    for (int row = wid; row < RVQ * CODES; row += 4) {
        float v = cbs[row * D + lane];
        float ss = waveSum(v * v);
        scb[row * CBSTRIDE + lane] = v / (sqrtf(ss) + 1e-12f);
    }
    __syncthreads();

    int jj = lane & 15, qq = lane >> 4;
    // per-lane codebook fragment: cbr[r][tt] = cbn[r][jj][qq*16+tt]
    float cbr[RVQ][16];
    #pragma unroll
    for (int r = 0; r < RVQ; ++r)
        #pragma unroll
        for (int tt = 0; tt < 16; ++tt)
            cbr[r][tt] = scb[(r * CODES + jj) * CBSTRIDE + qq * 16 + tt];

    float mu = stats[lane] * (1.0f / NN);
    float var = stats[64 + lane] * (1.0f / NN) - mu * mu;
    float scale = rsqrtf(var + BN_EPS) * gamma[lane];
    float shift = beta[lane] - mu * scale;

    float closs = 0.f;
    int wg = blockIdx.x * 4 + wid;
    int wstep = gridDim.x * 4;

    for (int n = wg; n < NN; n += wstep) {
        float hpv = hp[n * D + lane];
        float hn = fmaxf(hpv * scale + shift, 0.f);
        hp[n * D + lane] = hn;
        if (first_layer) x_local[n * D + lane] = hn;
        else x_local[n * D + lane] += hn;

        float res = hn;
        int bis[RVQ];
        #pragma unroll
        for (int r = 0; r < RVQ; ++r) {
            sres[t] = res;                       // wave-private slot, no barrier
            float rc[16];
            #pragma unroll
            for (int i = 0; i < 4; ++i) {
                float4 v4 = *((const float4*)&sres[wid * 64 + qq * 16 + 4 * i]);
                rc[4 * i + 0] = v4.x; rc[4 * i + 1] = v4.y;
                rc[4 * i + 2] = v4.z; rc[4 * i + 3] = v4.w;
            }
            float p = 0.f;
            #pragma unroll
            for (int tt = 0; tt < 16; ++tt) p += rc[tt] * cbr[r][tt];
            p += __shfl_xor(p, 16, 64);
            p += __shfl_xor(p, 32, 64);
            float bv = p;
            int bi = jj;
            #pragma unroll
            for (int off = 8; off; off >>= 1) {
                float ov = __shfl_xor(bv, off, 64);
                int oi = __shfl_xor(bi, off, 64);
                if (ov > bv || (ov == bv && oi < bi)) { bv = ov; bi = oi; }
            }
            float q = scb[(r * CODES + bi) * CBSTRIDE + lane];
            float d = q - res;
            closs += d * d;
            res -= q;
            bis[r] = bi;
        }
        if (lane == 0) {
            ids_out[n * (L * RVQ) + layer * RVQ + 0] = (float)bis[0];
            ids_out[n * (L * RVQ) + layer * RVQ + 1] = (float)bis[1];
            ids_out[n * (L * RVQ) + layer * RVQ + 2] = (float)bis[2];
        }
    }

    closs = waveSum(closs);
    if (lane == 0) sred[wid] = closs;
    __syncthreads();
    if (t == 0) {
        float tot = (sred[0] + sred[1]) + (sred[2] + sred[3]);
        atomicAdd(commit, tot * (COMMIT_W / (float)(NN * D)));
    }
}

// ---------------- Heads ----------------
__global__ __launch_bounds__(256) void k_head(
    const float* __restrict__ x_local,
    const float* __restrict__ Wp, const float* __restrict__ bp,
    const float* __restrict__ Wg, const float* __restrict__ bg,
    float* __restrict__ pred, float* __restrict__ gnn) {
    int t = threadIdx.x, lane = t & 63, wid = t >> 6;
    int jsafe = (lane < 9) ? lane : 0;

    float wp[D], wg[D];
    #pragma unroll
    for (int k = 0; k < D; ++k) {
        wp[k] = Wp[k * D + lane];
        wg[k] = Wg[k * 9 + jsafe];
    }
    float bpv = bp[lane], bgv = bg[jsafe];

    int w = blockIdx.x * 4 + wid;
    int wstep = gridDim.x * 4;
    for (int n = w; n < NN; n += wstep) {
        const float4* xrow = (const float4*)(x_local + (size_t)n * D);
        float p = 0.f, g = 0.f;
        #pragma unroll
        for (int j = 0; j < 16; ++j) {
            float4 x4 = xrow[j];
            p += x4.x * wp[4 * j + 0]; g += x4.x * wg[4 * j + 0];
            p += x4.y * wp[4 * j + 1]; g += x4.y * wg[4 * j + 1];
            p += x4.z * wp[4 * j + 2]; g += x4.z * wg[4 * j + 2];
            p += x4.w * wp[4 * j + 3]; g += x4.w * wg[4 * j + 3];
        }
        pred[(size_t)n * D + lane] = p + bpv;
        if (lane < 9) gnn[(size_t)n * 9 + lane] = g + bgv;
    }
}

extern "C" void kernel_launch(void* const* d_in, const int* in_sizes, int n_in,
                              void* d_out, int out_size, void* d_ws, size_t ws_size,
                              hipStream_t stream) {
    const float* x   = (const float*)d_in[0];
    const int* ei    = (const int*)d_in[1];
    const float* Wa  = (const float*)d_in[2];
    const float* ba  = (const float*)d_in[3];
    const float* Wr  = (const float*)d_in[4];
    const float* Wl  = (const float*)d_in[5];
    const float* bl  = (const float*)d_in[6];
    const float* gamma = (const float*)d_in[7];
    const float* beta  = (const float*)d_in[8];
    const float* cbs = (const float*)d_in[9];
    const float* Wp  = (const float*)d_in[10];
    const float* bp  = (const float*)d_in[11];
    const float* Wg  = (const float*)d_in[12];
    const float* bg  = (const float*)d_in[13];

    const int* src = ei;
    const int* dst = ei + NE;

    int*   ws_i  = (int*)d_ws;
    float* ws_f  = (float*)d_ws;
    int* rowptr  = ws_i + OFS_ROWPTR;
    int* cnt     = ws_i + OFS_CNT;
    int* cursor  = ws_i + OFS_CURSOR;
    int* bsums   = ws_i + OFS_BSUMS;
    int* boffs   = ws_i + OFS_BOFFS;
    float* stats = ws_f + OFS_STATS;
    int* csr_src = ws_i + OFS_CSR;
    float* hA    = ws_f + OFS_HA;
    float* hB    = ws_f + OFS_HB;
    float* xloc  = ws_f + OFS_XLOC;
    float* part  = ws_f + OFS_PART;

    float* out    = (float*)d_out;
    float* pred   = out + OUT_PRED;
    float* commit = out + OUT_COMMIT;
    float* ids    = out + OUT_IDS;
    float* gnn    = out + OUT_GNN;

    hipMemsetAsync(cnt, 0, NN * sizeof(int), stream);
    hipMemsetAsync(commit, 0, sizeof(float), stream);

    // CSR build
    k_count<<<(NE + 255) / 256, 256, 0, stream>>>(dst, cnt);
    int nscan = (NN + SCAN_B - 1) / SCAN_B;  // 98
    k_scan1<<<nscan, SCAN_B, 0, stream>>>(cnt, rowptr, bsums);
    k_scan2<<<1, SCAN_B, 0, stream>>>(bsums, boffs, nscan);
    k_scan3<<<nscan, SCAN_B, 0, stream>>>(rowptr, boffs);
    k_cursor<<<(NN + 1023) / 1024, 1024, 0, stream>>>(rowptr, cursor);
    k_fill<<<(NE + 255) / 256, 256, 0, stream>>>(src, dst, cursor, csr_src);
    k_sortrows<<<(NN + 255) / 256, 256, 0, stream>>>(rowptr, csr_src);

    // layers
    const float* hin = x;
    float* bufs[2] = {hA, hB};
    int gather_blocks = (NN + 15) / 16;  // 4 nodes/wave, 4 waves/block
    for (int i = 0; i < L; ++i) {
        float* hp = bufs[i & 1];
        k_gather<<<gather_blocks, 256, 0, stream>>>(hin, rowptr, csr_src, hp);
        k_matvec<<<GRID_A, 256, 0, stream>>>(hin, hp,
                                             Wa + i * D * D, ba + i * D,
                                             Wr + i * D * D, Wl + i * D * D, bl + i * D,
                                             part);
        k_red_stats<<<1, 128, 0, stream>>>(part, stats + i * 128);
        k_layer_b<<<GRID_A, 256, 0, stream>>>(hp, stats + i * 128,
                                              gamma + i * D, beta + i * D,
                                              cbs + i * RVQ * CODES * D,
                                              xloc, ids, i, commit, (i == 0) ? 1 : 0);
        hin = hp;
    }

    // heads
    k_head<<<2048, 256, 0, stream>>>(xloc, Wp, bp, Wg, bg, pred, gnn);
}

// Round 6
// 1059.922 us; speedup vs baseline: 1.5030x; 1.5030x over previous
//
#include <hip/hip_runtime.h>
#include <math.h>

#define NN 100000
#define NE 1000000
#define D 64
#define L 3
#define RVQ 3
#define CODES 16
#define BN_EPS 1e-5f
#define COMMIT_W 0.25f

#define GRID_A 2048   // blocks for matvec/layer_b kernels (fixed: partials + node mapping)

// ---------------- ws layout (in 4-byte units) ----------------
#define OFS_ROWPTR 0           // 100001 ints
#define OFS_CNT    100016      // 100000 ints
#define OFS_CURSOR 200032      // 100000 ints
#define OFS_BSUMS  300048      // 128 ints
#define OFS_BOFFS  300176      // 128 ints
#define OFS_STATS  300304      // 3*128 floats (sum[64],sumsq[64] per layer)
#define OFS_CSR    300800      // 1000000 ints
#define OFS_HA     1300800     // 6400000 floats
#define OFS_HB     7700800     // 6400000 floats
#define OFS_XLOC   14100800    // 6400000 floats
#define OFS_PART   20500800    // 2048*128 floats = 262144
// total = 20,762,944 * 4 B ~= 83 MB

// ---------------- d_out layout (floats) ----------------
#define OUT_PRED   0
#define OUT_COMMIT (NN * D)                       // 6,400,000
#define OUT_IDS    (NN * D + 1)                   // 6,400,001
#define OUT_GNN    (NN * D + 1 + NN * (L * RVQ))  // 7,300,001

static __device__ __forceinline__ float waveSum(float v) {
    #pragma unroll
    for (int off = 32; off; off >>= 1) v += __shfl_xor(v, off, 64);
    return v;
}

// ---------------- CSR build ----------------
__global__ void k_count(const int* __restrict__ dst, int* __restrict__ cnt) {
    int e = blockIdx.x * blockDim.x + threadIdx.x;
    if (e < NE) atomicAdd(&cnt[dst[e]], 1);
}

#define SCAN_B 1024
__global__ void k_scan1(const int* __restrict__ cnt, int* __restrict__ rowptr,
                        int* __restrict__ bsums) {
    __shared__ int sm[SCAN_B];
    int t = threadIdx.x;
    int i = blockIdx.x * SCAN_B + t;
    int v = (i < NN) ? cnt[i] : 0;
    sm[t] = v;
    __syncthreads();
    for (int off = 1; off < SCAN_B; off <<= 1) {
        int add = (t >= off) ? sm[t - off] : 0;
        __syncthreads();
        sm[t] += add;
        __syncthreads();
    }
    if (i < NN) rowptr[i + 1] = sm[t];
    if (t == SCAN_B - 1) bsums[blockIdx.x] = sm[t];
}

__global__ void k_scan2(const int* __restrict__ bsums, int* __restrict__ boffs, int nb) {
    __shared__ int sm[SCAN_B];
    int t = threadIdx.x;
    int orig = (t < nb) ? bsums[t] : 0;
    sm[t] = orig;
    __syncthreads();
    for (int off = 1; off < SCAN_B; off <<= 1) {
        int add = (t >= off) ? sm[t - off] : 0;
        __syncthreads();
        sm[t] += add;
        __syncthreads();
    }
    if (t < nb) boffs[t] = sm[t] - orig;  // exclusive
}

__global__ void k_scan3(int* __restrict__ rowptr, const int* __restrict__ boffs) {
    int i = blockIdx.x * SCAN_B + threadIdx.x;
    if (i < NN) rowptr[i + 1] += boffs[blockIdx.x];
    if (i == 0) rowptr[0] = 0;
}

__global__ void k_cursor(const int* __restrict__ rowptr, int* __restrict__ cursor) {
    int i = blockIdx.x * blockDim.x + threadIdx.x;
    if (i < NN) cursor[i] = rowptr[i];
}

__global__ void k_fill(const int* __restrict__ src, const int* __restrict__ dst,
                       int* __restrict__ cursor, int* __restrict__ csr_src) {
    int e = blockIdx.x * blockDim.x + threadIdx.x;
    if (e < NE) {
        int p = atomicAdd(&cursor[dst[e]], 1);
        csr_src[p] = src[e];
    }
}

// Canonicalize row order so the neighbor-sum order is deterministic.
__global__ void k_sortrows(const int* __restrict__ rowptr, int* __restrict__ csr) {
    int n = blockIdx.x * blockDim.x + threadIdx.x;
    if (n >= NN) return;
    int r0 = rowptr[n], r1 = rowptr[n + 1];
    for (int i = r0 + 1; i < r1; ++i) {
        int v = csr[i];
        int j = i - 1;
        while (j >= r0 && csr[j] > v) { csr[j + 1] = csr[j]; --j; }
        csr[j + 1] = v;
    }
}

// ---------------- Gather: mean of neighbor rows -> mean_out ----------------
// One wave per node (R4 config — the 4-node/quarter variant regressed: each
// load instruction touched 4 scattered line-groups). 8-deep unrolled row
// loads for MLP. Neighbor sum strictly sequential over sorted row.
__global__ __launch_bounds__(256) void k_gather(
    const float* __restrict__ h, const int* __restrict__ rowptr,
    const int* __restrict__ csr_src, float* __restrict__ mean_out) {
    int t = threadIdx.x;
    int lane = t & 63, wid = t >> 6;
    int n = blockIdx.x * 4 + wid;
    if (n >= NN) return;

    int r0 = rowptr[n], r1 = rowptr[n + 1];
    float s = 0.f;
    for (int base = r0; base < r1; base += 64) {
        int last = r1 - 1;
        int ii = base + lane;
        int idx = csr_src[(ii <= last) ? ii : last];  // coalesced, clamped
        int m = r1 - base;
        if (m > 64) m = 64;
        int j = 0;
        for (; j + 8 <= m; j += 8) {
            int i0 = __shfl(idx, j + 0, 64), i1 = __shfl(idx, j + 1, 64);
            int i2 = __shfl(idx, j + 2, 64), i3 = __shfl(idx, j + 3, 64);
            int i4 = __shfl(idx, j + 4, 64), i5 = __shfl(idx, j + 5, 64);
            int i6 = __shfl(idx, j + 6, 64), i7 = __shfl(idx, j + 7, 64);
            float v0 = h[i0 * D + lane], v1 = h[i1 * D + lane];
            float v2 = h[i2 * D + lane], v3 = h[i3 * D + lane];
            float v4 = h[i4 * D + lane], v5 = h[i5 * D + lane];
            float v6 = h[i6 * D + lane], v7 = h[i7 * D + lane];
            s += v0; s += v1; s += v2; s += v3;
            s += v4; s += v5; s += v6; s += v7;
        }
        for (; j + 4 <= m; j += 4) {
            int i0 = __shfl(idx, j + 0, 64), i1 = __shfl(idx, j + 1, 64);
            int i2 = __shfl(idx, j + 2, 64), i3 = __shfl(idx, j + 3, 64);
            float v0 = h[i0 * D + lane], v1 = h[i1 * D + lane];
            float v2 = h[i2 * D + lane], v3 = h[i3 * D + lane];
            s += v0; s += v1; s += v2; s += v3;
        }
        for (; j < m; ++j) {
            int i0 = __shfl(idx, j, 64);
            s += h[i0 * D + lane];
        }
    }
    float deg = (float)(r1 - r0);
    mean_out[n * D + lane] = s / fmaxf(deg, 1.0f);
}

// ---------------- Matvec: SAGE transform + skip linear + BN stat partials --
// lane = output channel. Weights loaded once and PINNED into VGPRs via empty
// inline asm (defeats the compiler's remat-inside-loop heuristic that R4's
// VGPR_Count=128 exposed). Activation rows are wave-uniform (readfirstlane)
// -> SMEM scalar broadcast loads, FMAs are v_fmac v,s,v. launch_bounds(256,1)
// allows ~220 VGPRs -> 2 waves/SIMD. Accumulation order identical to R2-R4
// (bit-identical output).
__global__ __launch_bounds__(256, 1) void k_matvec(
    const float* __restrict__ h, float* __restrict__ hp,
    const float* __restrict__ Wa, const float* __restrict__ ba,
    const float* __restrict__ Wr, const float* __restrict__ Wl,
    const float* __restrict__ bl, float* __restrict__ partials) {
    __shared__ float red[2][4][D];
    int t = threadIdx.x, lane = t & 63, wid = t >> 6;

    float wa[D], wr[D], wl[D];
    #pragma unroll
    for (int k = 0; k < D; ++k) {
        wa[k] = Wa[k * D + lane];
        wr[k] = Wr[k * D + lane];
        wl[k] = Wl[k * D + lane];
    }
    // Pin each weight into a VGPR: opaque to the optimizer -> no remat/reload.
    #pragma unroll
    for (int k = 0; k < D; ++k) {
        asm volatile("" : "+v"(wa[k]), "+v"(wr[k]), "+v"(wl[k]));
    }
    float bav = ba[lane], blv = bl[lane];

    int wg = blockIdx.x * 4 + wid;
    int wstep = GRID_A * 4;
    float accS = 0.f, accQ = 0.f;

    for (int n = wg; n < NN; n += wstep) {
        int nu = __builtin_amdgcn_readfirstlane(n);
        const float4* mrow = (const float4*)(hp + (size_t)nu * D);
        const float4* hrow = (const float4*)(h + (size_t)nu * D);
        float a = 0.f, r = 0.f, lv = 0.f;
        #pragma unroll
        for (int j = 0; j < 16; ++j) {
            float4 m4 = mrow[j];
            float4 h4 = hrow[j];
            a += m4.x * wa[4 * j + 0]; r += h4.x * wr[4 * j + 0]; lv += h4.x * wl[4 * j + 0];
            a += m4.y * wa[4 * j + 1]; r += h4.y * wr[4 * j + 1]; lv += h4.y * wl[4 * j + 1];
            a += m4.z * wa[4 * j + 2]; r += h4.z * wr[4 * j + 2]; lv += h4.z * wl[4 * j + 2];
            a += m4.w * wa[4 * j + 3]; r += h4.w * wr[4 * j + 3]; lv += h4.w * wl[4 * j + 3];
        }
        float sage = a + bav + r;
        float ss = waveSum(sage * sage);
        float inv = 1.0f / (sqrtf(ss) + 1e-12f);
        float hpv = sage * inv + lv + blv;
        hp[(size_t)n * D + lane] = hpv;
        accS += hpv;
        accQ += hpv * hpv;
    }

    red[0][wid][lane] = accS;
    red[1][wid][lane] = accQ;
    __syncthreads();
    if (wid == 0) {
        float s0 = (red[0][0][lane] + red[0][1][lane]) + (red[0][2][lane] + red[0][3][lane]);
        float q0 = (red[1][0][lane] + red[1][1][lane]) + (red[1][2][lane] + red[1][3][lane]);
        partials[blockIdx.x * 128 + lane]      = s0;
        partials[blockIdx.x * 128 + 64 + lane] = q0;
    }
}

// Deterministic fixed-order reduction of BN stat partials (no atomics).
__global__ void k_red_stats(const float* __restrict__ part, float* __restrict__ stats) {
    int t = threadIdx.x;  // 0..127
    float s0 = 0.f, s1 = 0.f, s2 = 0.f, s3 = 0.f;
    for (int b = 0; b < GRID_A; b += 4) {
        s0 += part[(b + 0) * 128 + t];
        s1 += part[(b + 1) * 128 + t];
        s2 += part[(b + 2) * 128 + t];
        s3 += part[(b + 3) * 128 + t];
    }
    stats[t] = (s0 + s1) + (s2 + s3);
}

// ---------------- Layer part B: BN + ReLU + x_local accumulate + residual VQ
#define CBSTRIDE 65
__global__ __launch_bounds__(256) void k_layer_b(
    float* __restrict__ hp,              // in: pre-BN h'; out: post-ReLU h
    const float* __restrict__ stats,
    const float* __restrict__ gamma, const float* __restrict__ beta,
    const float* __restrict__ cbs,       // [RVQ][CODES][D] for this layer
    float* __restrict__ x_local,
    float* __restrict__ ids_out,         // [NN][L*RVQ] region base
    int layer, float* __restrict__ commit, int first_layer) {
    __shared__ float scb[RVQ * CODES * CBSTRIDE];
    __shared__ float sres[256];
    __shared__ float sred[4];
    int t = threadIdx.x, lane = t & 63, wid = t >> 6;

    // normalize codebook rows into LDS (identical math to before)
    for (int row = wid; row < RVQ * CODES; row += 4) {
        float v = cbs[row * D + lane];
        float ss = waveSum(v * v);
        scb[row * CBSTRIDE + lane] = v / (sqrtf(ss) + 1e-12f);
    }
    __syncthreads();

    int jj = lane & 15, qq = lane >> 4;
    // per-lane codebook fragment: cbr[r][tt] = cbn[r][jj][qq*16+tt]
    float cbr[RVQ][16];
    #pragma unroll
    for (int r = 0; r < RVQ; ++r)
        #pragma unroll
        for (int tt = 0; tt < 16; ++tt)
            cbr[r][tt] = scb[(r * CODES + jj) * CBSTRIDE + qq * 16 + tt];

    float mu = stats[lane] * (1.0f / NN);
    float var = stats[64 + lane] * (1.0f / NN) - mu * mu;
    float scale = rsqrtf(var + BN_EPS) * gamma[lane];
    float shift = beta[lane] - mu * scale;

    float closs = 0.f;
    int wg = blockIdx.x * 4 + wid;
    int wstep = gridDim.x * 4;

    for (int n = wg; n < NN; n += wstep) {
        float hpv = hp[n * D + lane];
        float hn = fmaxf(hpv * scale + shift, 0.f);
        hp[n * D + lane] = hn;
        if (first_layer) x_local[n * D + lane] = hn;
        else x_local[n * D + lane] += hn;

        float res = hn;
        int bis[RVQ];
        #pragma unroll
        for (int r = 0; r < RVQ; ++r) {
            sres[t] = res;                       // wave-private slot, no barrier
            float rc[16];
            #pragma unroll
            for (int i = 0; i < 4; ++i) {
                float4 v4 = *((const float4*)&sres[wid * 64 + qq * 16 + 4 * i]);
                rc[4 * i + 0] = v4.x; rc[4 * i + 1] = v4.y;
                rc[4 * i + 2] = v4.z; rc[4 * i + 3] = v4.w;
            }
            float p = 0.f;
            #pragma unroll
            for (int tt = 0; tt < 16; ++tt) p += rc[tt] * cbr[r][tt];
            p += __shfl_xor(p, 16, 64);
            p += __shfl_xor(p, 32, 64);
            float bv = p;
            int bi = jj;
            #pragma unroll
            for (int off = 8; off; off >>= 1) {
                float ov = __shfl_xor(bv, off, 64);
                int oi = __shfl_xor(bi, off, 64);
                if (ov > bv || (ov == bv && oi < bi)) { bv = ov; bi = oi; }
            }
            float q = scb[(r * CODES + bi) * CBSTRIDE + lane];
            float d = q - res;
            closs += d * d;
            res -= q;
            bis[r] = bi;
        }
        if (lane == 0) {
            ids_out[n * (L * RVQ) + layer * RVQ + 0] = (float)bis[0];
            ids_out[n * (L * RVQ) + layer * RVQ + 1] = (float)bis[1];
            ids_out[n * (L * RVQ) + layer * RVQ + 2] = (float)bis[2];
        }
    }

    closs = waveSum(closs);
    if (lane == 0) sred[wid] = closs;
    __syncthreads();
    if (t == 0) {
        float tot = (sred[0] + sred[1]) + (sred[2] + sred[3]);
        atomicAdd(commit, tot * (COMMIT_W / (float)(NN * D)));
    }
}

// ---------------- Heads ----------------
__global__ __launch_bounds__(256, 2) void k_head(
    const float* __restrict__ x_local,
    const float* __restrict__ Wp, const float* __restrict__ bp,
    const float* __restrict__ Wg, const float* __restrict__ bg,
    float* __restrict__ pred, float* __restrict__ gnn) {
    int t = threadIdx.x, lane = t & 63, wid = t >> 6;
    int jsafe = (lane < 9) ? lane : 0;

    float wp[D], wg[D];
    #pragma unroll
    for (int k = 0; k < D; ++k) {
        wp[k] = Wp[k * D + lane];
        wg[k] = Wg[k * 9 + jsafe];
    }
    float bpv = bp[lane], bgv = bg[jsafe];

    int w = blockIdx.x * 4 + wid;
    int wstep = gridDim.x * 4;
    for (int n = w; n < NN; n += wstep) {
        int nu = __builtin_amdgcn_readfirstlane(n);
        const float4* xrow = (const float4*)(x_local + (size_t)nu * D);
        float p = 0.f, g = 0.f;
        #pragma unroll
        for (int j = 0; j < 16; ++j) {
            float4 x4 = xrow[j];
            p += x4.x * wp[4 * j + 0]; g += x4.x * wg[4 * j + 0];
            p += x4.y * wp[4 * j + 1]; g += x4.y * wg[4 * j + 1];
            p += x4.z * wp[4 * j + 2]; g += x4.z * wg[4 * j + 2];
            p += x4.w * wp[4 * j + 3]; g += x4.w * wg[4 * j + 3];
        }
        pred[(size_t)n * D + lane] = p + bpv;
        if (lane < 9) gnn[(size_t)n * 9 + lane] = g + bgv;
    }
}

extern "C" void kernel_launch(void* const* d_in, const int* in_sizes, int n_in,
                              void* d_out, int out_size, void* d_ws, size_t ws_size,
                              hipStream_t stream) {
    const float* x   = (const float*)d_in[0];
    const int* ei    = (const int*)d_in[1];
    const float* Wa  = (const float*)d_in[2];
    const float* ba  = (const float*)d_in[3];
    const float* Wr  = (const float*)d_in[4];
    const float* Wl  = (const float*)d_in[5];
    const float* bl  = (const float*)d_in[6];
    const float* gamma = (const float*)d_in[7];
    const float* beta  = (const float*)d_in[8];
    const float* cbs = (const float*)d_in[9];
    const float* Wp  = (const float*)d_in[10];
    const float* bp  = (const float*)d_in[11];
    const float* Wg  = (const float*)d_in[12];
    const float* bg  = (const float*)d_in[13];

    const int* src = ei;
    const int* dst = ei + NE;

    int*   ws_i  = (int*)d_ws;
    float* ws_f  = (float*)d_ws;
    int* rowptr  = ws_i + OFS_ROWPTR;
    int* cnt     = ws_i + OFS_CNT;
    int* cursor  = ws_i + OFS_CURSOR;
    int* bsums   = ws_i + OFS_BSUMS;
    int* boffs   = ws_i + OFS_BOFFS;
    float* stats = ws_f + OFS_STATS;
    int* csr_src = ws_i + OFS_CSR;
    float* hA    = ws_f + OFS_HA;
    float* hB    = ws_f + OFS_HB;
    float* xloc  = ws_f + OFS_XLOC;
    float* part  = ws_f + OFS_PART;

    float* out    = (float*)d_out;
    float* pred   = out + OUT_PRED;
    float* commit = out + OUT_COMMIT;
    float* ids    = out + OUT_IDS;
    float* gnn    = out + OUT_GNN;

    hipMemsetAsync(cnt, 0, NN * sizeof(int), stream);
    hipMemsetAsync(commit, 0, sizeof(float), stream);

    // CSR build
    k_count<<<(NE + 255) / 256, 256, 0, stream>>>(dst, cnt);
    int nscan = (NN + SCAN_B - 1) / SCAN_B;  // 98
    k_scan1<<<nscan, SCAN_B, 0, stream>>>(cnt, rowptr, bsums);
    k_scan2<<<1, SCAN_B, 0, stream>>>(bsums, boffs, nscan);
    k_scan3<<<nscan, SCAN_B, 0, stream>>>(rowptr, boffs);
    k_cursor<<<(NN + 1023) / 1024, 1024, 0, stream>>>(rowptr, cursor);
    k_fill<<<(NE + 255) / 256, 256, 0, stream>>>(src, dst, cursor, csr_src);
    k_sortrows<<<(NN + 255) / 256, 256, 0, stream>>>(rowptr, csr_src);

    // layers
    const float* hin = x;
    float* bufs[2] = {hA, hB};
    for (int i = 0; i < L; ++i) {
        float* hp = bufs[i & 1];
        k_gather<<<(NN + 3) / 4, 256, 0, stream>>>(hin, rowptr, csr_src, hp);
        k_matvec<<<GRID_A, 256, 0, stream>>>(hin, hp,
                                             Wa + i * D * D, ba + i * D,
                                             Wr + i * D * D, Wl + i * D * D, bl + i * D,
                                             part);
        k_red_stats<<<1, 128, 0, stream>>>(part, stats + i * 128);
        k_layer_b<<<GRID_A, 256, 0, stream>>>(hp, stats + i * 128,
                                              gamma + i * D, beta + i * D,
                                              cbs + i * RVQ * CODES * D,
                                              xloc, ids, i, commit, (i == 0) ? 1 : 0);
        hin = hp;
    }

    // heads
    k_head<<<2048, 256, 0, stream>>>(xloc, Wp, bp, Wg, bg, pred, gnn);
}

// Round 7
// 910.446 us; speedup vs baseline: 1.7498x; 1.1642x over previous
//
#include <hip/hip_runtime.h>
#include <math.h>

#define NN 100000
#define NE 1000000
#define D 64
#define L 3
#define RVQ 3
#define CODES 16
#define BN_EPS 1e-5f
#define COMMIT_W 0.25f

#define GRID_A 2048   // blocks for matvec/layer_b kernels (fixed: partials + node mapping)

// ---------------- ws layout (in 4-byte units) ----------------
#define OFS_ROWPTR 0           // 100001 ints
#define OFS_CNT    100016      // 100000 ints
#define OFS_CURSOR 200032      // 100000 ints
#define OFS_BSUMS  300048      // 128 ints
#define OFS_BOFFS  300176      // 128 ints
#define OFS_STATS  300304      // 3*128 floats (sum[64],sumsq[64] per layer)
#define OFS_CSR    300800      // 1000000 ints
#define OFS_HA     1300800     // 6400000 floats
#define OFS_HB     7700800     // 6400000 floats
#define OFS_XLOC   14100800    // 6400000 floats
#define OFS_PART   20500800    // 2048*128 floats = 262144
// total = 20,762,944 * 4 B ~= 83 MB

// ---------------- d_out layout (floats) ----------------
#define OUT_PRED   0
#define OUT_COMMIT (NN * D)                       // 6,400,000
#define OUT_IDS    (NN * D + 1)                   // 6,400,001
#define OUT_GNN    (NN * D + 1 + NN * (L * RVQ))  // 7,300,001

static __device__ __forceinline__ float waveSum(float v) {
    #pragma unroll
    for (int off = 32; off; off >>= 1) v += __shfl_xor(v, off, 64);
    return v;
}

// ---------------- CSR build ----------------
__global__ void k_count(const int* __restrict__ dst, int* __restrict__ cnt) {
    int e = blockIdx.x * blockDim.x + threadIdx.x;
    if (e < NE) atomicAdd(&cnt[dst[e]], 1);
}

#define SCAN_B 1024
__global__ void k_scan1(const int* __restrict__ cnt, int* __restrict__ rowptr,
                        int* __restrict__ bsums) {
    __shared__ int sm[SCAN_B];
    int t = threadIdx.x;
    int i = blockIdx.x * SCAN_B + t;
    int v = (i < NN) ? cnt[i] : 0;
    sm[t] = v;
    __syncthreads();
    for (int off = 1; off < SCAN_B; off <<= 1) {
        int add = (t >= off) ? sm[t - off] : 0;
        __syncthreads();
        sm[t] += add;
        __syncthreads();
    }
    if (i < NN) rowptr[i + 1] = sm[t];
    if (t == SCAN_B - 1) bsums[blockIdx.x] = sm[t];
}

__global__ void k_scan2(const int* __restrict__ bsums, int* __restrict__ boffs, int nb) {
    __shared__ int sm[SCAN_B];
    int t = threadIdx.x;
    int orig = (t < nb) ? bsums[t] : 0;
    sm[t] = orig;
    __syncthreads();
    for (int off = 1; off < SCAN_B; off <<= 1) {
        int add = (t >= off) ? sm[t - off] : 0;
        __syncthreads();
        sm[t] += add;
        __syncthreads();
    }
    if (t < nb) boffs[t] = sm[t] - orig;  // exclusive
}

__global__ void k_scan3(int* __restrict__ rowptr, const int* __restrict__ boffs) {
    int i = blockIdx.x * SCAN_B + threadIdx.x;
    if (i < NN) rowptr[i + 1] += boffs[blockIdx.x];
    if (i == 0) rowptr[0] = 0;
}

__global__ void k_cursor(const int* __restrict__ rowptr, int* __restrict__ cursor) {
    int i = blockIdx.x * blockDim.x + threadIdx.x;
    if (i < NN) cursor[i] = rowptr[i];
}

__global__ void k_fill(const int* __restrict__ src, const int* __restrict__ dst,
                       int* __restrict__ cursor, int* __restrict__ csr_src) {
    int e = blockIdx.x * blockDim.x + threadIdx.x;
    if (e < NE) {
        int p = atomicAdd(&cursor[dst[e]], 1);
        csr_src[p] = src[e];
    }
}

// Canonicalize row order so the neighbor-sum order is deterministic.
__global__ void k_sortrows(const int* __restrict__ rowptr, int* __restrict__ csr) {
    int n = blockIdx.x * blockDim.x + threadIdx.x;
    if (n >= NN) return;
    int r0 = rowptr[n], r1 = rowptr[n + 1];
    for (int i = r0 + 1; i < r1; ++i) {
        int v = csr[i];
        int j = i - 1;
        while (j >= r0 && csr[j] > v) { csr[j + 1] = csr[j]; --j; }
        csr[j + 1] = v;
    }
}

// ---------------- Gather: mean of neighbor rows -> mean_out ----------------
// One wave per node; 8-deep unrolled row loads for MLP. Neighbor sum strictly
// sequential over sorted row (bit-deterministic).
__global__ __launch_bounds__(256) void k_gather(
    const float* __restrict__ h, const int* __restrict__ rowptr,
    const int* __restrict__ csr_src, float* __restrict__ mean_out) {
    int t = threadIdx.x;
    int lane = t & 63, wid = t >> 6;
    int n = blockIdx.x * 4 + wid;
    if (n >= NN) return;

    int r0 = rowptr[n], r1 = rowptr[n + 1];
    float s = 0.f;
    for (int base = r0; base < r1; base += 64) {
        int last = r1 - 1;
        int ii = base + lane;
        int idx = csr_src[(ii <= last) ? ii : last];  // coalesced, clamped
        int m = r1 - base;
        if (m > 64) m = 64;
        int j = 0;
        for (; j + 8 <= m; j += 8) {
            int i0 = __shfl(idx, j + 0, 64), i1 = __shfl(idx, j + 1, 64);
            int i2 = __shfl(idx, j + 2, 64), i3 = __shfl(idx, j + 3, 64);
            int i4 = __shfl(idx, j + 4, 64), i5 = __shfl(idx, j + 5, 64);
            int i6 = __shfl(idx, j + 6, 64), i7 = __shfl(idx, j + 7, 64);
            float v0 = h[i0 * D + lane], v1 = h[i1 * D + lane];
            float v2 = h[i2 * D + lane], v3 = h[i3 * D + lane];
            float v4 = h[i4 * D + lane], v5 = h[i5 * D + lane];
            float v6 = h[i6 * D + lane], v7 = h[i7 * D + lane];
            s += v0; s += v1; s += v2; s += v3;
            s += v4; s += v5; s += v6; s += v7;
        }
        for (; j + 4 <= m; j += 4) {
            int i0 = __shfl(idx, j + 0, 64), i1 = __shfl(idx, j + 1, 64);
            int i2 = __shfl(idx, j + 2, 64), i3 = __shfl(idx, j + 3, 64);
            float v0 = h[i0 * D + lane], v1 = h[i1 * D + lane];
            float v2 = h[i2 * D + lane], v3 = h[i3 * D + lane];
            s += v0; s += v1; s += v2; s += v3;
        }
        for (; j < m; ++j) {
            int i0 = __shfl(idx, j, 64);
            s += h[i0 * D + lane];
        }
    }
    float deg = (float)(r1 - r0);
    mean_out[n * D + lane] = s / fmaxf(deg, 1.0f);
}

// ---------------- Matvec: SAGE transform + skip linear + BN stat partials --
// lane = output channel. Activation rows staged through a WAVE-PRIVATE LDS
// double buffer: lanes 0-31 cooperatively prefetch node n+wstep's rows (2
// coalesced dwordx4 per wave) while the wave computes node n via broadcast
// ds_read_b128 (same-address across lanes = conflict-free; LDS pipe overlaps
// VALU). No barriers needed (buffer is wave-private). Replaces the serialized
// SMEM (s_load/lgkmcnt) activation chain of R4/R6. FMA expression order is
// identical to R2-R6 -> bit-identical output.
__global__ __launch_bounds__(256) void k_matvec(
    const float* __restrict__ h, float* __restrict__ hp,
    const float* __restrict__ Wa, const float* __restrict__ ba,
    const float* __restrict__ Wr, const float* __restrict__ Wl,
    const float* __restrict__ bl, float* __restrict__ partials) {
    __shared__ float red[2][4][D];
    __shared__ float lbuf[4][2][128];   // [wave][parity][mean(64) | h(64)]
    int t = threadIdx.x, lane = t & 63, wid = t >> 6;

    float wa[D], wr[D], wl[D];
    #pragma unroll
    for (int k = 0; k < D; ++k) {
        wa[k] = Wa[k * D + lane];
        wr[k] = Wr[k * D + lane];
        wl[k] = Wl[k * D + lane];
    }
    float bav = ba[lane], blv = bl[lane];

    int wg = blockIdx.x * 4 + wid;
    const int wstep = GRID_A * 4;
    float accS = 0.f, accQ = 0.f;

    int seg = lane >> 4;   // 0: stage mean row, 1: stage h row, 2/3: idle
    int sl  = lane & 15;

    // preload first node into parity 0 (every wave has >=1 node: wg < 8192)
    {
        float4 v = {0.f, 0.f, 0.f, 0.f};
        if (seg == 0)      v = *(const float4*)(hp + (size_t)wg * D + 4 * sl);
        else if (seg == 1) v = *(const float4*)(h  + (size_t)wg * D + 4 * sl);
        if (seg < 2) *(float4*)&lbuf[wid][0][seg * 64 + 4 * sl] = v;
    }

    int p = 0;
    for (int n = wg; n < NN; n += wstep) {
        int nn = n + wstep;
        bool havepf = (nn < NN);
        float4 pf = {0.f, 0.f, 0.f, 0.f};
        if (havepf && seg < 2) {
            const float* srcp = (seg == 0) ? hp : h;
            pf = *(const float4*)(srcp + (size_t)nn * D + 4 * sl);
        }

        const float* mb = &lbuf[wid][p][0];
        const float* hb = &lbuf[wid][p][64];
        float a = 0.f, r = 0.f, lv = 0.f;
        #pragma unroll
        for (int j = 0; j < 16; ++j) {
            float4 m4 = *(const float4*)(mb + 4 * j);   // broadcast ds_read_b128
            float4 h4 = *(const float4*)(hb + 4 * j);
            a += m4.x * wa[4 * j + 0]; r += h4.x * wr[4 * j + 0]; lv += h4.x * wl[4 * j + 0];
            a += m4.y * wa[4 * j + 1]; r += h4.y * wr[4 * j + 1]; lv += h4.y * wl[4 * j + 1];
            a += m4.z * wa[4 * j + 2]; r += h4.z * wr[4 * j + 2]; lv += h4.z * wl[4 * j + 2];
            a += m4.w * wa[4 * j + 3]; r += h4.w * wr[4 * j + 3]; lv += h4.w * wl[4 * j + 3];
        }
        float sage = a + bav + r;
        float ss = waveSum(sage * sage);
        float inv = 1.0f / (sqrtf(ss) + 1e-12f);
        float hpv = sage * inv + lv + blv;
        hp[(size_t)n * D + lane] = hpv;
        accS += hpv;
        accQ += hpv * hpv;

        if (havepf && seg < 2)
            *(float4*)&lbuf[wid][p ^ 1][seg * 64 + 4 * sl] = pf;
        p ^= 1;
    }

    red[0][wid][lane] = accS;
    red[1][wid][lane] = accQ;
    __syncthreads();
    if (wid == 0) {
        float s0 = (red[0][0][lane] + red[0][1][lane]) + (red[0][2][lane] + red[0][3][lane]);
        float q0 = (red[1][0][lane] + red[1][1][lane]) + (red[1][2][lane] + red[1][3][lane]);
        partials[blockIdx.x * 128 + lane]      = s0;
        partials[blockIdx.x * 128 + 64 + lane] = q0;
    }
}

// Parallel deterministic reduction of BN stat partials: one block per channel
// slot, fixed tree (replay-deterministic). Replaces the single-block serial
// loop that was latency-bound on 1 MB of L2 reads.
__global__ __launch_bounds__(256) void k_red_stats(
    const float* __restrict__ part, float* __restrict__ stats) {
    __shared__ float sm[256];
    int c = blockIdx.x;      // 0..127
    int i = threadIdx.x;     // 0..255
    float s = 0.f;
    #pragma unroll
    for (int k = 0; k < 8; ++k)
        s += part[(size_t)(i * 8 + k) * 128 + c];
    sm[i] = s;
    __syncthreads();
    #pragma unroll
    for (int off = 128; off >= 1; off >>= 1) {
        if (i < off) sm[i] += sm[i + off];
        __syncthreads();
    }
    if (i == 0) stats[c] = sm[0];
}

// ---------------- Layer part B: BN + ReLU + x_local accumulate + residual VQ
#define CBSTRIDE 65
__global__ __launch_bounds__(256) void k_layer_b(
    float* __restrict__ hp,              // in: pre-BN h'; out: post-ReLU h
    const float* __restrict__ stats,
    const float* __restrict__ gamma, const float* __restrict__ beta,
    const float* __restrict__ cbs,       // [RVQ][CODES][D] for this layer
    float* __restrict__ x_local,
    float* __restrict__ ids_out,         // [NN][L*RVQ] region base
    int layer, float* __restrict__ commit, int first_layer) {
    __shared__ float scb[RVQ * CODES * CBSTRIDE];
    __shared__ float sres[256];
    __shared__ float sred[4];
    int t = threadIdx.x, lane = t & 63, wid = t >> 6;

    // normalize codebook rows into LDS (identical math to before)
    for (int row = wid; row < RVQ * CODES; row += 4) {
        float v = cbs[row * D + lane];
        float ss = waveSum(v * v);
        scb[row * CBSTRIDE + lane] = v / (sqrtf(ss) + 1e-12f);
    }
    __syncthreads();

    int jj = lane & 15, qq = lane >> 4;
    // per-lane codebook fragment: cbr[r][tt] = cbn[r][jj][qq*16+tt]
    float cbr[RVQ][16];
    #pragma unroll
    for (int r = 0; r < RVQ; ++r)
        #pragma unroll
        for (int tt = 0; tt < 16; ++tt)
            cbr[r][tt] = scb[(r * CODES + jj) * CBSTRIDE + qq * 16 + tt];

    float mu = stats[lane] * (1.0f / NN);
    float var = stats[64 + lane] * (1.0f / NN) - mu * mu;
    float scale = rsqrtf(var + BN_EPS) * gamma[lane];
    float shift = beta[lane] - mu * scale;

    float closs = 0.f;
    int wg = blockIdx.x * 4 + wid;
    int wstep = gridDim.x * 4;

    for (int n = wg; n < NN; n += wstep) {
        float hpv = hp[n * D + lane];
        float hn = fmaxf(hpv * scale + shift, 0.f);
        hp[n * D + lane] = hn;
        if (first_layer) x_local[n * D + lane] = hn;
        else x_local[n * D + lane] += hn;

        float res = hn;
        int bis[RVQ];
        #pragma unroll
        for (int r = 0; r < RVQ; ++r) {
            sres[t] = res;                       // wave-private slot, no barrier
            float rc[16];
            #pragma unroll
            for (int i = 0; i < 4; ++i) {
                float4 v4 = *((const float4*)&sres[wid * 64 + qq * 16 + 4 * i]);
                rc[4 * i + 0] = v4.x; rc[4 * i + 1] = v4.y;
                rc[4 * i + 2] = v4.z; rc[4 * i + 3] = v4.w;
            }
            float p = 0.f;
            #pragma unroll
            for (int tt = 0; tt < 16; ++tt) p += rc[tt] * cbr[r][tt];
            p += __shfl_xor(p, 16, 64);
            p += __shfl_xor(p, 32, 64);
            float bv = p;
            int bi = jj;
            #pragma unroll
            for (int off = 8; off; off >>= 1) {
                float ov = __shfl_xor(bv, off, 64);
                int oi = __shfl_xor(bi, off, 64);
                if (ov > bv || (ov == bv && oi < bi)) { bv = ov; bi = oi; }
            }
            float q = scb[(r * CODES + bi) * CBSTRIDE + lane];
            float d = q - res;
            closs += d * d;
            res -= q;
            bis[r] = bi;
        }
        if (lane == 0) {
            ids_out[n * (L * RVQ) + layer * RVQ + 0] = (float)bis[0];
            ids_out[n * (L * RVQ) + layer * RVQ + 1] = (float)bis[1];
            ids_out[n * (L * RVQ) + layer * RVQ + 2] = (float)bis[2];
        }
    }

    closs = waveSum(closs);
    if (lane == 0) sred[wid] = closs;
    __syncthreads();
    if (t == 0) {
        float tot = (sred[0] + sred[1]) + (sred[2] + sred[3]);
        atomicAdd(commit, tot * (COMMIT_W / (float)(NN * D)));
    }
}

// ---------------- Heads ----------------
__global__ __launch_bounds__(256, 2) void k_head(
    const float* __restrict__ x_local,
    const float* __restrict__ Wp, const float* __restrict__ bp,
    const float* __restrict__ Wg, const float* __restrict__ bg,
    float* __restrict__ pred, float* __restrict__ gnn) {
    int t = threadIdx.x, lane = t & 63, wid = t >> 6;
    int jsafe = (lane < 9) ? lane : 0;

    float wp[D], wg[D];
    #pragma unroll
    for (int k = 0; k < D; ++k) {
        wp[k] = Wp[k * D + lane];
        wg[k] = Wg[k * 9 + jsafe];
    }
    float bpv = bp[lane], bgv = bg[jsafe];

    int w = blockIdx.x * 4 + wid;
    int wstep = gridDim.x * 4;
    for (int n = w; n < NN; n += wstep) {
        int nu = __builtin_amdgcn_readfirstlane(n);
        const float4* xrow = (const float4*)(x_local + (size_t)nu * D);
        float p = 0.f, g = 0.f;
        #pragma unroll
        for (int j = 0; j < 16; ++j) {
            float4 x4 = xrow[j];
            p += x4.x * wp[4 * j + 0]; g += x4.x * wg[4 * j + 0];
            p += x4.y * wp[4 * j + 1]; g += x4.y * wg[4 * j + 1];
            p += x4.z * wp[4 * j + 2]; g += x4.z * wg[4 * j + 2];
            p += x4.w * wp[4 * j + 3]; g += x4.w * wg[4 * j + 3];
        }
        pred[(size_t)n * D + lane] = p + bpv;
        if (lane < 9) gnn[(size_t)n * 9 + lane] = g + bgv;
    }
}

extern "C" void kernel_launch(void* const* d_in, const int* in_sizes, int n_in,
                              void* d_out, int out_size, void* d_ws, size_t ws_size,
                              hipStream_t stream) {
    const float* x   = (const float*)d_in[0];
    const int* ei    = (const int*)d_in[1];
    const float* Wa  = (const float*)d_in[2];
    const float* ba  = (const float*)d_in[3];
    const float* Wr  = (const float*)d_in[4];
    const float* Wl  = (const float*)d_in[5];
    const float* bl  = (const float*)d_in[6];
    const float* gamma = (const float*)d_in[7];
    const float* beta  = (const float*)d_in[8];
    const float* cbs = (const float*)d_in[9];
    const float* Wp  = (const float*)d_in[10];
    const float* bp  = (const float*)d_in[11];
    const float* Wg  = (const float*)d_in[12];
    const float* bg  = (const float*)d_in[13];

    const int* src = ei;
    const int* dst = ei + NE;

    int*   ws_i  = (int*)d_ws;
    float* ws_f  = (float*)d_ws;
    int* rowptr  = ws_i + OFS_ROWPTR;
    int* cnt     = ws_i + OFS_CNT;
    int* cursor  = ws_i + OFS_CURSOR;
    int* bsums   = ws_i + OFS_BSUMS;
    int* boffs   = ws_i + OFS_BOFFS;
    float* stats = ws_f + OFS_STATS;
    int* csr_src = ws_i + OFS_CSR;
    float* hA    = ws_f + OFS_HA;
    float* hB    = ws_f + OFS_HB;
    float* xloc  = ws_f + OFS_XLOC;
    float* part  = ws_f + OFS_PART;

    float* out    = (float*)d_out;
    float* pred   = out + OUT_PRED;
    float* commit = out + OUT_COMMIT;
    float* ids    = out + OUT_IDS;
    float* gnn    = out + OUT_GNN;

    hipMemsetAsync(cnt, 0, NN * sizeof(int), stream);
    hipMemsetAsync(commit, 0, sizeof(float), stream);

    // CSR build
    k_count<<<(NE + 255) / 256, 256, 0, stream>>>(dst, cnt);
    int nscan = (NN + SCAN_B - 1) / SCAN_B;  // 98
    k_scan1<<<nscan, SCAN_B, 0, stream>>>(cnt, rowptr, bsums);
    k_scan2<<<1, SCAN_B, 0, stream>>>(bsums, boffs, nscan);
    k_scan3<<<nscan, SCAN_B, 0, stream>>>(rowptr, boffs);
    k_cursor<<<(NN + 1023) / 1024, 1024, 0, stream>>>(rowptr, cursor);
    k_fill<<<(NE + 255) / 256, 256, 0, stream>>>(src, dst, cursor, csr_src);
    k_sortrows<<<(NN + 255) / 256, 256, 0, stream>>>(rowptr, csr_src);

    // layers
    const float* hin = x;
    float* bufs[2] = {hA, hB};
    for (int i = 0; i < L; ++i) {
        float* hp = bufs[i & 1];
        k_gather<<<(NN + 3) / 4, 256, 0, stream>>>(hin, rowptr, csr_src, hp);
        k_matvec<<<GRID_A, 256, 0, stream>>>(hin, hp,
                                             Wa + i * D * D, ba + i * D,
                                             Wr + i * D * D, Wl + i * D * D, bl + i * D,
                                             part);
        k_red_stats<<<128, 256, 0, stream>>>(part, stats + i * 128);
        k_layer_b<<<GRID_A, 256, 0, stream>>>(hp, stats + i * 128,
                                              gamma + i * D, beta + i * D,
                                              cbs + i * RVQ * CODES * D,
                                              xloc, ids, i, commit, (i == 0) ? 1 : 0);
        hin = hp;
    }

    // heads
    k_head<<<2048, 256, 0, stream>>>(xloc, Wp, bp, Wg, bg, pred, gnn);
}